// Round 1
// baseline (627.419 us; speedup 1.0000x reference)
//
#include <hip/hip_runtime.h>
#include <hip/hip_bf16.h>

typedef unsigned short u16;
typedef unsigned int u32;

typedef short bf16v8 __attribute__((ext_vector_type(8)));
typedef float f32v4 __attribute__((ext_vector_type(4)));

// ---------------- problem constants ----------------
constexpr int BB   = 64;
constexpr int TT   = 196;
constexpr int NTOK = BB * TT;   // 12544
constexpr int DD   = 512;
constexpr int FF   = 2048;
constexpr int EE   = 8;
constexpr int NBR  = 2;
constexpr int MT_MAX = 106;     // >= max sum of ceil(cnt_e/128) = 105

// LDS padded row stride (in bf16 elems) for 32-wide K tiles: 40*2B = 80B, 16B-aligned,
// bank pattern (20r+4c)%32 -> only 2-way aliasing (free on CDNA4).
constexpr int LDSK = 40;

__device__ __forceinline__ u16 f2bf(float f) {
    union { float f; u32 u; } v; v.f = f;
    u32 r = v.u + 0x7fffu + ((v.u >> 16) & 1u);
    return (u16)(r >> 16);
}

__device__ __forceinline__ float wave_sum(float v) {
    #pragma unroll
    for (int m = 32; m > 0; m >>= 1) v += __shfl_xor(v, m, 64);
    return v;
}

__device__ __forceinline__ float gelu_tanh(float v) {
    float t = tanhf(0.7978845608028654f * (v + 0.044715f * v * v * v));
    return 0.5f * v * (1.0f + t);
}

__device__ __forceinline__ float silu(float v) {
    return v / (1.0f + expf(-v));
}

// ---------------- transpose f32[R][C] -> bf16[C][R], batched ----------------
__global__ __launch_bounds__(256) void transpose_f32_bf16(
    const float* __restrict__ src, u16* __restrict__ dst, int R, int C)
{
    __shared__ float tile[32][33];
    size_t base = (size_t)blockIdx.z * R * C;
    src += base; dst += base;
    int tx = threadIdx.x, ty = threadIdx.y;
    int c0 = blockIdx.x * 32, r0 = blockIdx.y * 32;
    #pragma unroll
    for (int j = 0; j < 4; ++j)
        tile[ty + 8 * j][tx] = src[(size_t)(r0 + ty + 8 * j) * C + c0 + tx];
    __syncthreads();
    #pragma unroll
    for (int j = 0; j < 4; ++j)
        dst[(size_t)(c0 + ty + 8 * j) * R + r0 + tx] = f2bf(tile[tx][ty + 8 * j]);
}

// ---------------- LN + gate softmax/argmax (wave per token) ----------------
__global__ __launch_bounds__(256) void ln_gate_kernel(
    const float* __restrict__ x, const float* __restrict__ ln_g, const float* __restrict__ ln_b,
    const float* __restrict__ gate_w, const float* __restrict__ gate_b,
    u16* __restrict__ hA, u16* __restrict__ hB,
    int* __restrict__ idxb, float* __restrict__ pbuf)
{
    int wave = threadIdx.x >> 6, lane = threadIdx.x & 63;
    int tok = blockIdx.x * 4 + wave;
    const float* xr = x + (size_t)tok * DD + lane * 8;
    float4 v0 = *(const float4*)xr;
    float4 v1 = *(const float4*)(xr + 4);
    float xs[8] = {v0.x, v0.y, v0.z, v0.w, v1.x, v1.y, v1.z, v1.w};
    float s = 0.f, ss = 0.f;
    #pragma unroll
    for (int i = 0; i < 8; ++i) { s += xs[i]; ss += xs[i] * xs[i]; }
    s = wave_sum(s); ss = wave_sum(ss);
    float mu = s * (1.0f / DD);
    float var = ss * (1.0f / DD) - mu * mu;
    float rstd = rsqrtf(var + 1e-5f);

    #pragma unroll
    for (int br = 0; br < NBR; ++br) {
        u16* hb = br ? hB : hA;
        float part[8] = {0, 0, 0, 0, 0, 0, 0, 0};
        u16 hu[8];
        #pragma unroll
        for (int i = 0; i < 8; ++i) {
            int d = lane * 8 + i;
            float g = ln_g[br * DD + d], b = ln_b[br * DD + d];
            float h = (xs[i] - mu) * rstd * g + b;
            hu[i] = f2bf(h);
            const float* gw = gate_w + ((size_t)br * DD + d) * EE;
            float4 g0 = *(const float4*)gw;
            float4 g1 = *(const float4*)(gw + 4);
            part[0] += h * g0.x; part[1] += h * g0.y; part[2] += h * g0.z; part[3] += h * g0.w;
            part[4] += h * g1.x; part[5] += h * g1.y; part[6] += h * g1.z; part[7] += h * g1.w;
        }
        uint4 pk;
        pk.x = (u32)hu[0] | ((u32)hu[1] << 16);
        pk.y = (u32)hu[2] | ((u32)hu[3] << 16);
        pk.z = (u32)hu[4] | ((u32)hu[5] << 16);
        pk.w = (u32)hu[6] | ((u32)hu[7] << 16);
        *(uint4*)(hb + (size_t)tok * DD + lane * 8) = pk;

        float logit[8];
        #pragma unroll
        for (int e = 0; e < 8; ++e)
            logit[e] = wave_sum(part[e]) + gate_b[br * EE + e];
        float m = logit[0]; int bi = 0;
        #pragma unroll
        for (int e = 1; e < 8; ++e)
            if (logit[e] > m) { m = logit[e]; bi = e; }
        float sum = 0.f;
        #pragma unroll
        for (int e = 0; e < 8; ++e) sum += expf(logit[e] - m);
        if (lane == 0) {
            idxb[br * NTOK + tok] = bi;
            pbuf[br * NTOK + tok] = 1.0f / sum;   // top-1 softmax prob
        }
    }
}

// ---------------- routing ----------------
__global__ void route_kernel(const int* __restrict__ idxb, int* __restrict__ cnt,
                             int* __restrict__ list)
{
    int t = blockIdx.x * 256 + threadIdx.x;
    if (t >= NTOK) return;
    #pragma unroll
    for (int br = 0; br < NBR; ++br) {
        int e = idxb[br * NTOK + t];
        int slot = atomicAdd(&cnt[br * EE + e], 1);
        list[((size_t)(br * EE + e)) * NTOK + slot] = t;
    }
}

__global__ void tilestart_kernel(const int* __restrict__ cnt, int* __restrict__ ts)
{
    if (threadIdx.x == 0 && blockIdx.x == 0) {
        for (int br = 0; br < NBR; ++br) {
            int a = 0;
            ts[br * 9] = 0;
            for (int e = 0; e < EE; ++e) {
                a += (cnt[br * EE + e] + 127) >> 7;
                ts[br * 9 + e + 1] = a;
            }
        }
    }
}

// ---------------- grouped MFMA GEMM, 128x128 tile, BK=32 ----------------
// MODE 0: u = gelu(h @ W1 + b1)           A=h[NTOK][512]  B=w1t[E][2048][512]  -> u bf16
// MODE 1: moe (+)= p * (u @ W2 + b2)      A=u[NTOK][2048] B=w2t[E][512][2048]  -> moe f32
// MODE 2: out = x + s @ outw + out_b      A=s[NTOK][512]  B=owt[512][512]      -> out f32
template<int MODE>
__global__ __launch_bounds__(256, 2) void gemm_tile(
    const u16* __restrict__ A, const u16* __restrict__ Bt,
    const int* __restrict__ list, const int* __restrict__ ts, const int* __restrict__ cnt,
    const float* __restrict__ pbuf, const float* __restrict__ bias,
    u16* __restrict__ uout, float* __restrict__ fout,
    const float* __restrict__ xres, int addflag)
{
    constexpr int K = (MODE == 1) ? FF : DD;
    constexpr int N = (MODE == 0) ? FF : DD;

    __shared__ __align__(16) u16 As[128 * LDSK];
    __shared__ __align__(16) u16 Bs[128 * LDSK];
    __shared__ int rowtok[128];

    int mtile = blockIdx.x, ntile = blockIdx.y;
    int e = 0, cnt_e = NTOK, rb = 0;
    if constexpr (MODE != 2) {
        if (mtile >= ts[8]) return;
        while (mtile >= ts[e + 1]) ++e;
        rb = (mtile - ts[e]) * 128;
        cnt_e = cnt[e];
    }
    int tid = threadIdx.x;
    if (tid < 128) {
        if constexpr (MODE == 2) {
            rowtok[tid] = mtile * 128 + tid;
        } else {
            int gr = rb + tid;
            rowtok[tid] = (gr < cnt_e) ? list[(size_t)e * NTOK + gr]
                                       : list[(size_t)e * NTOK];
        }
    }
    __syncthreads();

    const u16* Bte = Bt + (size_t)e * N * K;
    int wave = tid >> 6, lane = tid & 63;
    int wm = wave >> 1, wn = wave & 1;

    f32v4 acc[4][4];
    #pragma unroll
    for (int mi = 0; mi < 4; ++mi)
        #pragma unroll
        for (int ni = 0; ni < 4; ++ni)
            acc[mi][ni] = (f32v4){0.f, 0.f, 0.f, 0.f};

    int r2 = tid >> 1, seg = tid & 1;
    int atok = rowtok[r2];
    const u16* asrc = A + (size_t)atok * K + seg * 16;
    const u16* bsrc = Bte + (size_t)(ntile * 128 + r2) * K + seg * 16;
    u16* adst = &As[r2 * LDSK + seg * 16];
    u16* bdst = &Bs[r2 * LDSK + seg * 16];

    int arow = (lane & 15) * LDSK + (lane >> 4) * 8;   // frag base within 16-row group

    for (int k0 = 0; k0 < K; k0 += 32) {
        uint4 av0 = *(const uint4*)(asrc + k0);
        uint4 av1 = *(const uint4*)(asrc + k0 + 8);
        uint4 bv0 = *(const uint4*)(bsrc + k0);
        uint4 bv1 = *(const uint4*)(bsrc + k0 + 8);
        *(uint4*)adst = av0; *(uint4*)(adst + 8) = av1;
        *(uint4*)bdst = bv0; *(uint4*)(bdst + 8) = bv1;
        __syncthreads();

        bf16v8 af[4], bfr[4];
        #pragma unroll
        for (int mi = 0; mi < 4; ++mi)
            af[mi] = *(const bf16v8*)&As[(wm * 64 + mi * 16) * LDSK + arow];
        #pragma unroll
        for (int ni = 0; ni < 4; ++ni)
            bfr[ni] = *(const bf16v8*)&Bs[(wn * 64 + ni * 16) * LDSK + arow];
        #pragma unroll
        for (int mi = 0; mi < 4; ++mi)
            #pragma unroll
            for (int ni = 0; ni < 4; ++ni)
                acc[mi][ni] = __builtin_amdgcn_mfma_f32_16x16x32_bf16(
                    af[mi], bfr[ni], acc[mi][ni], 0, 0, 0);
        __syncthreads();
    }

    // epilogue  (C/D frag: col = lane&15, row = (lane>>4)*4 + reg  [m89-verified])
    #pragma unroll
    for (int mi = 0; mi < 4; ++mi) {
        #pragma unroll
        for (int ni = 0; ni < 4; ++ni) {
            int col = ntile * 128 + wn * 64 + ni * 16 + (lane & 15);
            float bn = (MODE == 2) ? bias[col] : bias[(size_t)e * N + col];
            #pragma unroll
            for (int r = 0; r < 4; ++r) {
                int rr = wm * 64 + mi * 16 + (lane >> 4) * 4 + r;
                float v = acc[mi][ni][r] + bn;
                if constexpr (MODE == 0) {
                    if (rb + rr < cnt_e) {
                        int tok = rowtok[rr];
                        uout[(size_t)tok * FF + col] = f2bf(gelu_tanh(v));
                    }
                } else if constexpr (MODE == 1) {
                    if (rb + rr < cnt_e) {
                        int tok = rowtok[rr];
                        float val = v * pbuf[tok];
                        float* o = &fout[(size_t)tok * DD + col];
                        if (addflag) *o += val; else *o = val;
                    }
                } else {
                    size_t o = (size_t)(mtile * 128 + rr) * DD + col;
                    fout[o] = xres[o] + v;
                }
            }
        }
    }
}

// ---------------- eo = silu(emb) @ emb_w + emb_b  [64, 1024] ----------------
__global__ __launch_bounds__(256) void eo_kernel(
    const float* __restrict__ emb, const float* __restrict__ emb_w,
    const float* __restrict__ emb_b, float* __restrict__ eo)
{
    __shared__ float se[DD];
    int b = blockIdx.x, tid = threadIdx.x;
    #pragma unroll
    for (int i = tid; i < DD; i += 256)
        se[i] = silu(emb[(size_t)b * DD + i]);
    __syncthreads();
    float accv[4] = {0, 0, 0, 0};
    for (int k = 0; k < DD; ++k) {
        float sv = se[k];
        #pragma unroll
        for (int j = 0; j < 4; ++j)
            accv[j] += sv * emb_w[(size_t)k * 1024 + tid + 256 * j];
    }
    #pragma unroll
    for (int j = 0; j < 4; ++j) {
        int col = tid + 256 * j;
        eo[(size_t)b * 1024 + col] = accv[j] + emb_b[col];
    }
}

// ---------------- stylize: LN(moe/NB)*(1+scale)+shift -> silu -> bf16 ----------------
__global__ __launch_bounds__(256) void stylize_kernel(
    const float* __restrict__ moe, const float* __restrict__ eo,
    const float* __restrict__ sn_g, const float* __restrict__ sn_b,
    u16* __restrict__ sbuf)
{
    int wave = threadIdx.x >> 6, lane = threadIdx.x & 63;
    int tok = blockIdx.x * 4 + wave;
    int b = tok / TT;
    const float* mr = moe + (size_t)tok * DD + lane * 8;
    float4 v0 = *(const float4*)mr;
    float4 v1 = *(const float4*)(mr + 4);
    float os[8] = {v0.x, v0.y, v0.z, v0.w, v1.x, v1.y, v1.z, v1.w};
    #pragma unroll
    for (int i = 0; i < 8; ++i) os[i] *= (1.0f / NBR);
    float s = 0.f, ss = 0.f;
    #pragma unroll
    for (int i = 0; i < 8; ++i) { s += os[i]; ss += os[i] * os[i]; }
    s = wave_sum(s); ss = wave_sum(ss);
    float mu = s * (1.0f / DD);
    float var = ss * (1.0f / DD) - mu * mu;
    float rstd = rsqrtf(var + 1e-5f);
    u16 hu[8];
    #pragma unroll
    for (int i = 0; i < 8; ++i) {
        int d = lane * 8 + i;
        float h = (os[i] - mu) * rstd * sn_g[d] + sn_b[d];
        float sc = eo[(size_t)b * 1024 + d];
        float sh = eo[(size_t)b * 1024 + DD + d];
        h = h * (1.0f + sc) + sh;
        hu[i] = f2bf(silu(h));
    }
    uint4 pk;
    pk.x = (u32)hu[0] | ((u32)hu[1] << 16);
    pk.y = (u32)hu[2] | ((u32)hu[3] << 16);
    pk.z = (u32)hu[4] | ((u32)hu[5] << 16);
    pk.w = (u32)hu[6] | ((u32)hu[7] << 16);
    *(uint4*)(sbuf + (size_t)tok * DD + lane * 8) = pk;
}

// ---------------- host ----------------
extern "C" void kernel_launch(void* const* d_in, const int* in_sizes, int n_in,
                              void* d_out, int out_size, void* d_ws, size_t ws_size,
                              hipStream_t stream)
{
    const float* x      = (const float*)d_in[0];
    const float* emb    = (const float*)d_in[1];
    const float* ln_g   = (const float*)d_in[2];
    const float* ln_b   = (const float*)d_in[3];
    const float* gate_w = (const float*)d_in[4];
    const float* gate_b = (const float*)d_in[5];
    const float* w1     = (const float*)d_in[6];
    const float* b1     = (const float*)d_in[7];
    const float* w2     = (const float*)d_in[8];
    const float* b2     = (const float*)d_in[9];
    const float* emb_w  = (const float*)d_in[10];
    const float* emb_b  = (const float*)d_in[11];
    const float* sn_g   = (const float*)d_in[12];
    const float* sn_b   = (const float*)d_in[13];
    const float* out_w  = (const float*)d_in[14];
    const float* out_b  = (const float*)d_in[15];

    char* w = (char*)d_ws;
    size_t off = 0;
    auto take = [&](size_t bytes) -> void* {
        void* p = w + off;
        off = (off + bytes + 255) & ~(size_t)255;
        return p;
    };
    u16*   w1t  = (u16*)take((size_t)NBR * EE * FF * DD * 2);   // 33.5 MB  [NB][E][F][D]
    u16*   w2t  = (u16*)take((size_t)NBR * EE * FF * DD * 2);   // 33.5 MB  [NB][E][D][F]
    u16*   owt  = (u16*)take((size_t)DD * DD * 2);              // 0.5 MB   [D][D]
    u16*   hA   = (u16*)take((size_t)NTOK * DD * 2);            // 12.85 MB (reused as sbuf)
    u16*   hB   = (u16*)take((size_t)NTOK * DD * 2);            // 12.85 MB
    u16*   ubuf = (u16*)take((size_t)NTOK * FF * 2);            // 51.4 MB
    float* moe  = (float*)take((size_t)NTOK * DD * 4);          // 25.7 MB
    float* eo   = (float*)take((size_t)BB * 2 * DD * 4);        // 0.26 MB
    float* pbuf = (float*)take((size_t)NBR * NTOK * 4);
    int*   idxb = (int*)take((size_t)NBR * NTOK * 4);
    int*   cnt  = (int*)take((size_t)NBR * EE * 4);
    int*   ts   = (int*)take((size_t)NBR * 9 * 4);
    int*   list = (int*)take((size_t)NBR * EE * NTOK * 4);      // 0.8 MB
    (void)ws_size; (void)n_in; (void)in_sizes; (void)out_size;

    // 1. weight transposes -> bf16 [N][K]
    transpose_f32_bf16<<<dim3(FF / 32, DD / 32, NBR * EE), dim3(32, 8), 0, stream>>>(w1, w1t, DD, FF);
    transpose_f32_bf16<<<dim3(DD / 32, FF / 32, NBR * EE), dim3(32, 8), 0, stream>>>(w2, w2t, FF, DD);
    transpose_f32_bf16<<<dim3(DD / 32, DD / 32, 1), dim3(32, 8), 0, stream>>>(out_w, owt, DD, DD);

    // 2. LN + gate
    ln_gate_kernel<<<NTOK / 4, 256, 0, stream>>>(x, ln_g, ln_b, gate_w, gate_b, hA, hB, idxb, pbuf);

    // 3. routing
    hipMemsetAsync(cnt, 0, (size_t)NBR * EE * 4, stream);
    route_kernel<<<(NTOK + 255) / 256, 256, 0, stream>>>(idxb, cnt, list);
    tilestart_kernel<<<1, 64, 0, stream>>>(cnt, ts);

    // 4. grouped expert FFN per branch
    for (int br = 0; br < NBR; ++br) {
        const u16* h = br ? hB : hA;
        gemm_tile<0><<<dim3(MT_MAX, FF / 128), 256, 0, stream>>>(
            h, w1t + (size_t)br * EE * FF * DD,
            list + (size_t)br * EE * NTOK, ts + br * 9, cnt + br * EE,
            nullptr, b1 + (size_t)br * EE * FF,
            ubuf, nullptr, nullptr, 0);
        gemm_tile<1><<<dim3(MT_MAX, DD / 128), 256, 0, stream>>>(
            ubuf, w2t + (size_t)br * EE * FF * DD,
            list + (size_t)br * EE * NTOK, ts + br * 9, cnt + br * EE,
            pbuf + (size_t)br * NTOK, b2 + (size_t)br * EE * DD,
            nullptr, moe, nullptr, br);
    }

    // 5. stylization + output projection + residual
    eo_kernel<<<BB, 256, 0, stream>>>(emb, emb_w, emb_b, eo);
    stylize_kernel<<<NTOK / 4, 256, 0, stream>>>(moe, eo, sn_g, sn_b, hA);
    gemm_tile<2><<<dim3(NTOK / 128, DD / 128), 256, 0, stream>>>(
        hA, owt, nullptr, nullptr, nullptr, nullptr, out_b,
        nullptr, (float*)d_out, x, 0);
}

// Round 2
// 497.918 us; speedup vs baseline: 1.2601x; 1.2601x over previous
//
#include <hip/hip_runtime.h>
#include <hip/hip_bf16.h>

typedef unsigned short u16;
typedef unsigned int u32;

typedef short bf16v8 __attribute__((ext_vector_type(8)));
typedef float f32v4 __attribute__((ext_vector_type(4)));

// ---------------- problem constants ----------------
constexpr int BB   = 64;
constexpr int TT   = 196;
constexpr int NTOK = BB * TT;   // 12544
constexpr int DD   = 512;
constexpr int FF   = 2048;
constexpr int EE   = 8;
constexpr int NBR  = 2;
constexpr int GE   = NBR * EE;  // 16 global experts
constexpr int MT1  = 106;       // max tiles per branch (105) + slack
constexpr int MT2  = 210;       // max tiles both branches

// meta layout (ints): [0..15] posbase, [17] ntiles_br0, [18] ntiles_br1,
// [19] ntiles_total, [20..229] tile->ge, [240..449] tile->rowbase
constexpr int M_NT0 = 17, M_NT1 = 18, M_NTT = 19, M_GE = 20, M_RB = 240;

__device__ __forceinline__ u16 f2bf(float f) {
    union { float f; u32 u; } v; v.f = f;
    u32 r = v.u + 0x7fffu + ((v.u >> 16) & 1u);
    return (u16)(r >> 16);
}

__device__ __forceinline__ float wave_sum(float v) {
    #pragma unroll
    for (int m = 32; m > 0; m >>= 1) v += __shfl_xor(v, m, 64);
    return v;
}

__device__ __forceinline__ float gelu_tanh(float v) {
    float z = 0.7978845608028654f * (v + 0.044715f * v * v * v);
    float az = fabsf(z);
    float e = __expf(-2.0f * az);
    float t = (1.0f - e) / (1.0f + e);          // tanh(|z|)
    t = (z < 0.0f) ? -t : t;
    return 0.5f * v * (1.0f + t);
}

__device__ __forceinline__ float silu(float v) {
    return v / (1.0f + __expf(-v));
}

// async global->LDS, 16B per lane; lds dest must be wave-uniform base
__device__ __forceinline__ void gload16(const u16* g, u16* l) {
    typedef const __attribute__((address_space(1))) unsigned gv_t;
    typedef __attribute__((address_space(3))) unsigned lv_t;
    __builtin_amdgcn_global_load_lds((gv_t*)g, (lv_t*)l, 16, 0, 0);
}

// ---------------- transpose f32[R][C] -> bf16[C][R], batched ----------------
__global__ __launch_bounds__(256) void transpose_f32_bf16(
    const float* __restrict__ src, u16* __restrict__ dst, int R, int C)
{
    __shared__ float tile[32][33];
    size_t base = (size_t)blockIdx.z * R * C;
    src += base; dst += base;
    int tx = threadIdx.x, ty = threadIdx.y;
    int c0 = blockIdx.x * 32, r0 = blockIdx.y * 32;
    #pragma unroll
    for (int j = 0; j < 4; ++j)
        tile[ty + 8 * j][tx] = src[(size_t)(r0 + ty + 8 * j) * C + c0 + tx];
    __syncthreads();
    #pragma unroll
    for (int j = 0; j < 4; ++j)
        dst[(size_t)(c0 + ty + 8 * j) * R + r0 + tx] = f2bf(tile[tx][ty + 8 * j]);
}

// ---------------- LN + gate softmax/argmax (wave per token) ----------------
__global__ __launch_bounds__(256) void ln_gate_kernel(
    const float* __restrict__ x, const float* __restrict__ ln_g, const float* __restrict__ ln_b,
    const float* __restrict__ gate_w, const float* __restrict__ gate_b,
    u16* __restrict__ hA, u16* __restrict__ hB,
    int* __restrict__ idxb, float* __restrict__ pbuf)
{
    int wave = threadIdx.x >> 6, lane = threadIdx.x & 63;
    int tok = blockIdx.x * 4 + wave;
    const float* xr = x + (size_t)tok * DD + lane * 8;
    float4 v0 = *(const float4*)xr;
    float4 v1 = *(const float4*)(xr + 4);
    float xs[8] = {v0.x, v0.y, v0.z, v0.w, v1.x, v1.y, v1.z, v1.w};
    float s = 0.f, ss = 0.f;
    #pragma unroll
    for (int i = 0; i < 8; ++i) { s += xs[i]; ss += xs[i] * xs[i]; }
    s = wave_sum(s); ss = wave_sum(ss);
    float mu = s * (1.0f / DD);
    float var = ss * (1.0f / DD) - mu * mu;
    float rstd = rsqrtf(var + 1e-5f);

    #pragma unroll
    for (int br = 0; br < NBR; ++br) {
        u16* hb = br ? hB : hA;
        float part[8] = {0, 0, 0, 0, 0, 0, 0, 0};
        u16 hu[8];
        #pragma unroll
        for (int i = 0; i < 8; ++i) {
            int d = lane * 8 + i;
            float g = ln_g[br * DD + d], b = ln_b[br * DD + d];
            float h = (xs[i] - mu) * rstd * g + b;
            hu[i] = f2bf(h);
            const float* gw = gate_w + ((size_t)br * DD + d) * EE;
            float4 g0 = *(const float4*)gw;
            float4 g1 = *(const float4*)(gw + 4);
            part[0] += h * g0.x; part[1] += h * g0.y; part[2] += h * g0.z; part[3] += h * g0.w;
            part[4] += h * g1.x; part[5] += h * g1.y; part[6] += h * g1.z; part[7] += h * g1.w;
        }
        uint4 pk;
        pk.x = (u32)hu[0] | ((u32)hu[1] << 16);
        pk.y = (u32)hu[2] | ((u32)hu[3] << 16);
        pk.z = (u32)hu[4] | ((u32)hu[5] << 16);
        pk.w = (u32)hu[6] | ((u32)hu[7] << 16);
        *(uint4*)(hb + (size_t)tok * DD + lane * 8) = pk;

        float logit[8];
        #pragma unroll
        for (int e = 0; e < 8; ++e)
            logit[e] = wave_sum(part[e]) + gate_b[br * EE + e];
        float m = logit[0]; int bi = 0;
        #pragma unroll
        for (int e = 1; e < 8; ++e)
            if (logit[e] > m) { m = logit[e]; bi = e; }
        float sum = 0.f;
        #pragma unroll
        for (int e = 0; e < 8; ++e) sum += __expf(logit[e] - m);
        if (lane == 0) {
            idxb[br * NTOK + tok] = bi;
            pbuf[br * NTOK + tok] = 1.0f / sum;   // top-1 softmax prob
        }
    }
}

// ---------------- routing ----------------
__global__ void route_kernel(const int* __restrict__ idxb, int* __restrict__ cnt,
                             int* __restrict__ list)
{
    int t = blockIdx.x * 256 + threadIdx.x;
    if (t >= NTOK) return;
    #pragma unroll
    for (int br = 0; br < NBR; ++br) {
        int e = idxb[br * NTOK + t];
        int slot = atomicAdd(&cnt[br * EE + e], 1);
        list[((size_t)(br * EE + e)) * NTOK + slot] = t;
    }
}

__global__ void tilestart_kernel(const int* __restrict__ cnt, int* __restrict__ meta, int ubig)
{
    if (threadIdx.x != 0 || blockIdx.x != 0) return;
    int n = 0, nt0 = 0;
    int pp = 0;
    for (int ge = 0; ge < GE; ++ge) {
        if (ge == 8) { nt0 = n; pp = ubig ? NTOK : 0; }
        meta[ge] = pp;
        pp += cnt[ge];
        int tiles = (cnt[ge] + 127) >> 7;
        for (int t = 0; t < tiles; ++t) {
            meta[M_GE + n] = ge;
            meta[M_RB + n] = t * 128;
            ++n;
        }
    }
    meta[M_NT0] = nt0;
    meta[M_NT1] = n - nt0;
    meta[M_NTT] = n;
}

// ---------------- grouped MFMA GEMM, 128x128 tile, BK=32, global_load_lds ----
// MODE 0: u[pos] = gelu(h[tok] @ W1[ge] + b1[ge])      A gathered via list
// MODE 1: moe{2}[tok] (+)= p * (u[pos] @ W2[ge] + b2)  A dense (routed order)
// MODE 2: dout = xres + A @ owt + out_b                A dense
// grid: (ntile, tileidx)
template<int MODE>
__global__ __launch_bounds__(256, 2) void gemm_tile(
    const u16* __restrict__ A0, const u16* __restrict__ A1,
    const u16* __restrict__ Bt,
    const int* __restrict__ meta, const int* __restrict__ cnt,
    const int* __restrict__ list, const float* __restrict__ pbuf,
    const float* __restrict__ bias,
    u16* __restrict__ uout, float* __restrict__ moeout,
    const float* __restrict__ xres, float* __restrict__ dout,
    int brsel, int addmode)
{
    constexpr int K = (MODE == 1) ? FF : DD;
    constexpr int N = (MODE == 0) ? FF : DD;

    __shared__ __align__(16) u16 As[128 * 32];
    __shared__ __align__(16) u16 Bs[128 * 32];
    __shared__ int rowtok[128];

    int ntile = blockIdx.x, ti = blockIdx.y;
    int ge = 0, rb = 0, cnt_e = NTOK, pb = 0;
    if constexpr (MODE == 2) {
        rb = ti * 128;
    } else {
        int nt0 = meta[M_NT0];
        int idx;
        if (brsel < 0) { if (ti >= meta[M_NTT]) return; idx = ti; }
        else {
            int lim = brsel ? meta[M_NT1] : nt0;
            if (ti >= lim) return;
            idx = ti + (brsel ? nt0 : 0);
        }
        ge = meta[M_GE + idx];
        rb = meta[M_RB + idx];
        cnt_e = cnt[ge];
        pb = meta[ge];
    }

    int tid = threadIdx.x, wave = tid >> 6, lane = tid & 63;
    const u16* Abase;
    if constexpr (MODE == 0) Abase = (ge >= 8) ? A1 : A0;
    else                     Abase = A0;
    const u16* Bte = Bt + (size_t)ge * FF * DD;

    // staging source addresses: thread covers rows r0 and r0+64, 16B chunk hi
    int r0 = wave * 16 + (lane >> 2);
    int hi = lane & 3;
    const u16 *aSrc0, *aSrc1, *bSrc0, *bSrc1;
    if constexpr (MODE == 0) {
        int lb = ge * NTOK;
        int g0 = rb + r0, g1 = g0 + 64;
        int t0 = (g0 < cnt_e) ? list[lb + g0] : list[lb];
        int t1 = (g1 < cnt_e) ? list[lb + g1] : list[lb];
        aSrc0 = Abase + (size_t)t0 * K + hi * 8;
        aSrc1 = Abase + (size_t)t1 * K + hi * 8;
    } else {
        size_t base = (MODE == 1) ? (size_t)(pb + rb) : (size_t)rb;
        aSrc0 = Abase + (base + r0) * (size_t)K + hi * 8;
        aSrc1 = Abase + (base + r0 + 64) * (size_t)K + hi * 8;
    }
    {
        int nrow = ntile * 128 + r0;
        bSrc0 = Bte + (size_t)nrow * K + hi * 8;
        bSrc1 = Bte + (size_t)(nrow + 64) * K + hi * 8;
    }

    if constexpr (MODE == 1) {
        if (tid < 128) {
            int g = rb + tid;
            rowtok[tid] = (g < cnt_e) ? list[ge * NTOK + g] : -1;
        }
    }

    // wave-uniform LDS destinations
    u16* aDst0 = As + wave * 512;
    u16* aDst1 = As + 2048 + wave * 512;
    u16* bDst0 = Bs + wave * 512;
    u16* bDst1 = Bs + 2048 + wave * 512;

    f32v4 acc[4][4];
    #pragma unroll
    for (int mi = 0; mi < 4; ++mi)
        #pragma unroll
        for (int ni = 0; ni < 4; ++ni)
            acc[mi][ni] = (f32v4){0.f, 0.f, 0.f, 0.f};

    int wm = wave >> 1, wn = wave & 1;
    int fr = lane & 15, fc = (lane >> 4) * 8;

    for (int k0 = 0; k0 < K; k0 += 32) {
        gload16(aSrc0, aDst0);
        gload16(aSrc1, aDst1);
        gload16(bSrc0, bDst0);
        gload16(bSrc1, bDst1);
        aSrc0 += 32; aSrc1 += 32; bSrc0 += 32; bSrc1 += 32;
        __syncthreads();

        bf16v8 af[4], bfr[4];
        #pragma unroll
        for (int mi = 0; mi < 4; ++mi)
            af[mi] = *(const bf16v8*)&As[(wm * 64 + mi * 16 + fr) * 32 + fc];
        #pragma unroll
        for (int ni = 0; ni < 4; ++ni)
            bfr[ni] = *(const bf16v8*)&Bs[(wn * 64 + ni * 16 + fr) * 32 + fc];
        #pragma unroll
        for (int mi = 0; mi < 4; ++mi)
            #pragma unroll
            for (int ni = 0; ni < 4; ++ni)
                acc[mi][ni] = __builtin_amdgcn_mfma_f32_16x16x32_bf16(
                    af[mi], bfr[ni], acc[mi][ni], 0, 0, 0);
        __syncthreads();
    }

    // epilogue  (C/D frag: col = lane&15, row = (lane>>4)*4 + reg)
    #pragma unroll
    for (int mi = 0; mi < 4; ++mi) {
        #pragma unroll
        for (int ni = 0; ni < 4; ++ni) {
            int col = ntile * 128 + wn * 64 + ni * 16 + fr;
            float bn = (MODE == 2) ? bias[col] : bias[(size_t)ge * N + col];
            #pragma unroll
            for (int r = 0; r < 4; ++r) {
                int rr = wm * 64 + mi * 16 + (lane >> 4) * 4 + r;
                float v = acc[mi][ni][r] + bn;
                if constexpr (MODE == 0) {
                    if (rb + rr < cnt_e)
                        uout[(size_t)(pb + rb + rr) * FF + col] = f2bf(gelu_tanh(v));
                } else if constexpr (MODE == 1) {
                    int tok = rowtok[rr];
                    if (tok >= 0) {
                        float val = v * pbuf[(ge >> 3) * NTOK + tok];
                        if (addmode == 2) {
                            moeout[((size_t)(ge >> 3) * NTOK + tok) * DD + col] = val;
                        } else {
                            float* o = &moeout[(size_t)tok * DD + col];
                            if (addmode) *o += val; else *o = val;
                        }
                    }
                } else {
                    size_t o = (size_t)(rb + rr) * DD + col;
                    dout[o] = xres[o] + v;
                }
            }
        }
    }
}

// ---------------- eo = silu(emb) @ emb_w + emb_b  [64, 1024] ----------------
// grid (4 colgroups, 16 batchgroups), 4 batches per block for weight reuse
__global__ __launch_bounds__(256) void eo_kernel(
    const float* __restrict__ emb, const float* __restrict__ emb_w,
    const float* __restrict__ emb_b, float* __restrict__ eo)
{
    __shared__ float se[4][DD];
    int tid = threadIdx.x;
    int b0 = blockIdx.y * 4;
    int c0 = blockIdx.x * 256 + tid;
    for (int i = tid; i < 4 * DD; i += 256) {
        int b = i >> 9, d = i & (DD - 1);
        se[b][d] = silu(emb[(size_t)(b0 + b) * DD + d]);
    }
    __syncthreads();
    float acc[4] = {0, 0, 0, 0};
    for (int k = 0; k < DD; ++k) {
        float wv = emb_w[(size_t)k * 1024 + c0];
        #pragma unroll
        for (int b = 0; b < 4; ++b) acc[b] += se[b][k] * wv;
    }
    float bb = emb_b[c0];
    #pragma unroll
    for (int b = 0; b < 4; ++b)
        eo[(size_t)(b0 + b) * 1024 + c0] = acc[b] + bb;
}

// ---------------- stylize: LN(moe/NB)*(1+scale)+shift -> silu -> bf16 -------
__global__ __launch_bounds__(256) void stylize_kernel(
    const float* __restrict__ moe, const float* __restrict__ eo,
    const float* __restrict__ sn_g, const float* __restrict__ sn_b,
    u16* __restrict__ sbuf, int two)
{
    int wave = threadIdx.x >> 6, lane = threadIdx.x & 63;
    int tok = blockIdx.x * 4 + wave;
    int b = tok / TT;
    const float* mr = moe + (size_t)tok * DD + lane * 8;
    float4 v0 = *(const float4*)mr;
    float4 v1 = *(const float4*)(mr + 4);
    float os[8] = {v0.x, v0.y, v0.z, v0.w, v1.x, v1.y, v1.z, v1.w};
    if (two) {
        const float* mr2 = mr + (size_t)NTOK * DD;
        float4 w0 = *(const float4*)mr2;
        float4 w1 = *(const float4*)(mr2 + 4);
        os[0] += w0.x; os[1] += w0.y; os[2] += w0.z; os[3] += w0.w;
        os[4] += w1.x; os[5] += w1.y; os[6] += w1.z; os[7] += w1.w;
    }
    #pragma unroll
    for (int i = 0; i < 8; ++i) os[i] *= (1.0f / NBR);
    float s = 0.f, ss = 0.f;
    #pragma unroll
    for (int i = 0; i < 8; ++i) { s += os[i]; ss += os[i] * os[i]; }
    s = wave_sum(s); ss = wave_sum(ss);
    float mu = s * (1.0f / DD);
    float var = ss * (1.0f / DD) - mu * mu;
    float rstd = rsqrtf(var + 1e-5f);
    u16 hu[8];
    #pragma unroll
    for (int i = 0; i < 8; ++i) {
        int d = lane * 8 + i;
        float h = (os[i] - mu) * rstd * sn_g[d] + sn_b[d];
        float sc = eo[(size_t)b * 1024 + d];
        float sh = eo[(size_t)b * 1024 + DD + d];
        h = h * (1.0f + sc) + sh;
        hu[i] = f2bf(silu(h));
    }
    uint4 pk;
    pk.x = (u32)hu[0] | ((u32)hu[1] << 16);
    pk.y = (u32)hu[2] | ((u32)hu[3] << 16);
    pk.z = (u32)hu[4] | ((u32)hu[5] << 16);
    pk.w = (u32)hu[6] | ((u32)hu[7] << 16);
    *(uint4*)(sbuf + (size_t)tok * DD + lane * 8) = pk;
}

// ---------------- host ----------------
extern "C" void kernel_launch(void* const* d_in, const int* in_sizes, int n_in,
                              void* d_out, int out_size, void* d_ws, size_t ws_size,
                              hipStream_t stream)
{
    const float* x      = (const float*)d_in[0];
    const float* emb    = (const float*)d_in[1];
    const float* ln_g   = (const float*)d_in[2];
    const float* ln_b   = (const float*)d_in[3];
    const float* gate_w = (const float*)d_in[4];
    const float* gate_b = (const float*)d_in[5];
    const float* w1     = (const float*)d_in[6];
    const float* b1     = (const float*)d_in[7];
    const float* w2     = (const float*)d_in[8];
    const float* b2     = (const float*)d_in[9];
    const float* emb_w  = (const float*)d_in[10];
    const float* emb_b  = (const float*)d_in[11];
    const float* sn_g   = (const float*)d_in[12];
    const float* sn_b   = (const float*)d_in[13];
    const float* out_w  = (const float*)d_in[14];
    const float* out_b  = (const float*)d_in[15];
    (void)n_in; (void)in_sizes; (void)out_size;

    // sizes
    const size_t szW   = (size_t)GE * FF * DD * 2;          // 33.5 MB each
    const size_t szOwt = (size_t)DD * DD * 2;
    const size_t szH   = (size_t)NTOK * DD * 2;             // 12.85 MB
    const size_t szEo  = (size_t)BB * 2 * DD * 4;
    const size_t szP   = (size_t)NBR * NTOK * 4;
    const size_t szCnt = 256, szMeta = 4096;
    const size_t szList = (size_t)GE * NTOK * 4;
    const size_t szU1  = ((size_t)NTOK + 128) * FF * 2;     // 51.9 MB
    const size_t szU2  = ((size_t)2 * NTOK + 128) * FF * 2; // 103.3 MB
    const size_t szM1  = (size_t)NTOK * DD * 4;             // 25.7 MB
    const size_t szM2  = (size_t)2 * NTOK * DD * 4;         // 51.4 MB

    auto align256 = [](size_t v) { return (v + 255) & ~(size_t)255; };
    size_t fixed = align256(szW) + align256(szW) + align256(szOwt) + align256(szH) * 2 +
                   align256(szEo) + align256(szP) * 2 + align256(szCnt) + align256(szMeta) +
                   align256(szList);
    bool combined = ws_size >= fixed + align256(szU2) + align256(szM2) + (1u << 20);

    char* w = (char*)d_ws;
    size_t off = 0;
    auto take = [&](size_t bytes) -> void* {
        void* p = w + off;
        off = align256(off + bytes);
        return p;
    };
    u16*   w1t  = (u16*)take(szW);
    u16*   w2t  = (u16*)take(szW);
    u16*   owt  = (u16*)take(szOwt);
    u16*   hA   = (u16*)take(szH);       // reused as sbuf
    u16*   hB   = (u16*)take(szH);
    float* eo   = (float*)take(szEo);
    float* pbuf = (float*)take(szP);
    int*   idxb = (int*)take(szP);
    int*   cnt  = (int*)take(szCnt);
    int*   meta = (int*)take(szMeta);
    int*   list = (int*)take(szList);
    u16*   ubuf = (u16*)take(combined ? szU2 : szU1);
    float* moe  = (float*)take(combined ? szM2 : szM1);

    // 1. weight transposes -> bf16 [N][K]
    transpose_f32_bf16<<<dim3(FF / 32, DD / 32, GE), dim3(32, 8), 0, stream>>>(w1, w1t, DD, FF);
    transpose_f32_bf16<<<dim3(DD / 32, FF / 32, GE), dim3(32, 8), 0, stream>>>(w2, w2t, FF, DD);
    transpose_f32_bf16<<<dim3(DD / 32, DD / 32, 1), dim3(32, 8), 0, stream>>>(out_w, owt, DD, DD);

    // 2. LN + gate
    ln_gate_kernel<<<NTOK / 4, 256, 0, stream>>>(x, ln_g, ln_b, gate_w, gate_b, hA, hB, idxb, pbuf);

    // 3. routing
    hipMemsetAsync(cnt, 0, 64, stream);
    route_kernel<<<(NTOK + 255) / 256, 256, 0, stream>>>(idxb, cnt, list);
    tilestart_kernel<<<1, 64, 0, stream>>>(cnt, meta, combined ? 1 : 0);

    // 4. grouped expert FFN
    if (combined) {
        gemm_tile<0><<<dim3(FF / 128, MT2), 256, 0, stream>>>(
            hA, hB, w1t, meta, cnt, list, nullptr, b1,
            ubuf, nullptr, nullptr, nullptr, -1, 0);
        gemm_tile<1><<<dim3(DD / 128, MT2), 256, 0, stream>>>(
            ubuf, nullptr, w2t, meta, cnt, list, pbuf, b2,
            nullptr, moe, nullptr, nullptr, -1, 2);
    } else {
        for (int br = 0; br < NBR; ++br) {
            gemm_tile<0><<<dim3(FF / 128, MT1), 256, 0, stream>>>(
                hA, hB, w1t, meta, cnt, list, nullptr, b1,
                ubuf, nullptr, nullptr, nullptr, br, 0);
            gemm_tile<1><<<dim3(DD / 128, MT1), 256, 0, stream>>>(
                ubuf, nullptr, w2t, meta, cnt, list, pbuf, b2,
                nullptr, moe, nullptr, nullptr, br, br);
        }
    }

    // 5. stylization + output projection + residual
    eo_kernel<<<dim3(4, 16), 256, 0, stream>>>(emb, emb_w, emb_b, eo);
    stylize_kernel<<<NTOK / 4, 256, 0, stream>>>(moe, eo, sn_g, sn_b, hA, combined ? 1 : 0);
    gemm_tile<2><<<dim3(DD / 128, NTOK / 128), 256, 0, stream>>>(
        hA, nullptr, owt, meta, cnt, list, nullptr, out_b,
        nullptr, nullptr, x, (float*)d_out, 0, 0);
}